// Round 3
// baseline (91.018 us; speedup 1.0000x reference)
//
#include <hip/hip_runtime.h>
#include <hip/hip_bf16.h>
#include <stdint.h>

typedef __bf16 bf16x8 __attribute__((ext_vector_type(8)));
typedef __bf16 bf16x2 __attribute__((ext_vector_type(2)));
typedef float f32x4 __attribute__((ext_vector_type(4)));

#define D 128
#define BQ 64
#define BK 64
#define NCH 8           // K-tiles per chunk-block
#define PT_STRIDE 72    // bf16 units per P transit row (64 + 8)

static __device__ __forceinline__ uint16_t to_bf16_bits(float a) {
    __bf16 h = (__bf16)a;
    return __builtin_bit_cast(uint16_t, h);
}
static __device__ __forceinline__ uint32_t pack2(float a, float b) {
    bf16x2 v; v[0] = (__bf16)a; v[1] = (__bf16)b;
    return __builtin_bit_cast(uint32_t, v);
}

// ---------------------------------------------------------------------------
// prep: K -> KF (bf16, fragment-linear), V -> VF (bf16, transposed frag-linear)
// KF tile layout: elem K[jf*16+m][ss*32+hi*8+e] at ((jf*4+ss)*64 + hi*16+m)*8 + e
// VF tile layout: elem V[s*32+hi*8+e][d0*16+m] at ((d0*2+s)*64 + hi*16+m)*8 + e
// => every fragment slice is 64 lanes x 16B = 1KB contiguous.
// ---------------------------------------------------------------------------
__global__ __launch_bounds__(256, 2) void la_prep(
    const float* __restrict__ K, const float* __restrict__ V,
    uint16_t* __restrict__ KF, uint16_t* __restrict__ VF, int n)
{
    __shared__ uint16_t Lt[128][PT_STRIDE];  // V-tile transposed: [dv][j], 18KB

    const int tid = threadIdx.x;
    const int jt  = blockIdx.x;
    const int bh  = blockIdx.y;
    const size_t tile = (size_t)(bh * (n / BK) + jt) * (BK * D);

    // ---- K: cast + permute into fragment order (no LDS needed) ----
    {
        const float* Ks = K + (size_t)bh * n * D + (size_t)jt * BK * D;
        uint16_t* KFt = KF + tile;
        #pragma unroll
        for (int i = 0; i < 8; ++i) {
            int idx = tid + 256 * i;          // float4 index in 64x128 tile
            int j = idx >> 5;
            int d = (idx & 31) * 4;
            float4 a = *(const float4*)(Ks + (size_t)idx * 4);
            int jf = j >> 4, m = j & 15, ss = d >> 5, hi = (d >> 3) & 3, e0 = d & 7;
            uint2 w; w.x = pack2(a.x, a.y); w.y = pack2(a.z, a.w);
            *(uint2*)&KFt[(size_t)(((jf * 4 + ss) * 64 + hi * 16 + m) * 8 + e0)] = w;
        }
    }
    // ---- V: transpose via LDS, then write fragment order coalesced ----
    {
        const float* Vs = V + (size_t)bh * n * D + (size_t)jt * BK * D;
        #pragma unroll
        for (int i = 0; i < 8; ++i) {
            int idx = tid + 256 * i;
            int j = idx >> 5;
            int d = (idx & 31) * 4;
            float4 a = *(const float4*)(Vs + (size_t)idx * 4);
            Lt[d + 0][j] = to_bf16_bits(a.x);
            Lt[d + 1][j] = to_bf16_bits(a.y);
            Lt[d + 2][j] = to_bf16_bits(a.z);
            Lt[d + 3][j] = to_bf16_bits(a.w);
        }
    }
    __syncthreads();
    {
        uint16_t* VFt = VF + tile;
        // thread t writes 32 consecutive bf16 (64B) at offset t*32
        int d0 = tid >> 5, s = (tid >> 4) & 1, hi = (tid >> 2) & 3, m4 = (tid & 3) * 4;
        uint4 w[4];
        #pragma unroll
        for (int mm = 0; mm < 4; ++mm)
            w[mm] = *(const uint4*)&Lt[d0 * 16 + m4 + mm][s * 32 + hi * 8];
        #pragma unroll
        for (int mm = 0; mm < 4; ++mm)
            *(uint4*)&VFt[(size_t)tid * 32 + mm * 8] = w[mm];
    }
}

// ---------------------------------------------------------------------------
// main: barrier-free; all MFMA fragments direct from global (frag-linear).
// Only per-wave P-transit LDS remains.
// ---------------------------------------------------------------------------
__global__ __launch_bounds__(256, 2) void la_main(
    const float* __restrict__ Q, const uint16_t* __restrict__ KF,
    const uint16_t* __restrict__ VF, float* __restrict__ O, int n, int nqt)
{
    __shared__ uint16_t Pt[4][16 * PT_STRIDE];  // 9216B, wave-private slices

    const int tid  = threadIdx.x;
    const int wave = tid >> 6;
    const int lane = tid & 63;
    const int m    = lane & 15;
    const int hi   = lane >> 4;

    // ---- decode blockIdx.x -> (qt, chunk): big qt dispatch first ----
    int x = blockIdx.x;
    int qt = nqt - 1;
    while (true) {
        int nc = qt / NCH + 1;           // ceil((qt+1)/NCH)
        if (x < nc) break;
        x -= nc; --qt;
    }
    int j0 = x * NCH;
    int j1 = j0 + NCH; if (j1 > qt + 1) j1 = qt + 1;
    const bool multi = (qt >= NCH);

    const int bh = blockIdx.y;
    const int h  = bh & 7;
    const float slope = exp2f(-(float)(h + 1));

    // decay banding: tiles with slope*dist > 9 contribute < ~0.1 abs
    const int band = ((9 << (h + 1)) + 63) / 64 + 1;
    { int jlo = qt + 1 - band; if (jlo > j0) j0 = jlo; }
    if (j0 >= j1) return;  // memset covers fully-banded chunks

    const size_t baseF = (size_t)(bh * (n / BK)) * (BK * D);
    const uint16_t* KFb = KF + baseF;
    const uint16_t* VFb = VF + baseF;

    const int qrow0 = qt * BQ + wave * 16;

    // ---- Q fragments (A-layout: row=m, k=32*ss+8*hi+e) from f32 global ----
    bf16x8 qf[4];
    {
        const float* qp = Q + (size_t)bh * n * D + (size_t)(qrow0 + m) * D + hi * 8;
        #pragma unroll
        for (int s = 0; s < 4; ++s) {
            float4 a = *(const float4*)(qp + s * 32);
            float4 b = *(const float4*)(qp + s * 32 + 4);
            bf16x8 f;
            f[0] = (__bf16)a.x; f[1] = (__bf16)a.y; f[2] = (__bf16)a.z; f[3] = (__bf16)a.w;
            f[4] = (__bf16)b.x; f[5] = (__bf16)b.y; f[6] = (__bf16)b.z; f[7] = (__bf16)b.w;
            qf[s] = f;
        }
    }

    float ei[4], ej[4];
    #pragma unroll
    for (int r = 0; r < 4; ++r)   ei[r] = __expf(-slope * (float)(4 * hi + r));
    #pragma unroll
    for (int jf = 0; jf < 4; ++jf) ej[jf] = __expf(slope * (float)(jf * 16 + m));

    f32x4 acc[8];
    #pragma unroll
    for (int i = 0; i < 8; ++i) acc[i] = (f32x4){0.f, 0.f, 0.f, 0.f};

    uint16_t* PtW = &Pt[wave][0];

    for (int jt = j0; jt < j1; ++jt) {
        const uint16_t* KFt = KFb + (size_t)jt * (BK * D);
        const uint16_t* VFt = VFb + (size_t)jt * (BK * D);

        const float Cs = __expf(-slope * (float)(qrow0 - jt * BK));
        float fi[4];
        #pragma unroll
        for (int r = 0; r < 4; ++r) fi[r] = Cs * ei[r];
        const bool diag = (jt == qt);

        // ---- S = Q K^T (16x64), decay+mask, transit to LDS ----
        #pragma unroll
        for (int jf = 0; jf < 4; ++jf) {
            f32x4 s = (f32x4){0.f, 0.f, 0.f, 0.f};
            #pragma unroll
            for (int ss = 0; ss < 4; ++ss) {
                bf16x8 kf = *(const bf16x8*)&KFt[(size_t)(((jf * 4 + ss) * 64 + lane) * 8)];
                s = __builtin_amdgcn_mfma_f32_16x16x32_bf16(qf[ss], kf, s, 0, 0, 0);
            }
            #pragma unroll
            for (int r = 0; r < 4; ++r) {
                float val = s[r] * (fi[r] * ej[jf]);
                if (diag) {
                    int iloc = (qrow0 - jt * BK) + 4 * hi + r;
                    int jloc = jf * 16 + m;
                    if (iloc < jloc) val = 0.f;
                }
                PtW[(4 * hi + r) * PT_STRIDE + jf * 16 + m] = to_bf16_bits(val);
            }
        }

        // ---- O += P V (fragments direct from global) ----
        bf16x8 pa0 = *(const bf16x8*)&PtW[m * PT_STRIDE + hi * 8];
        bf16x8 pa1 = *(const bf16x8*)&PtW[m * PT_STRIDE + 32 + hi * 8];
        #pragma unroll
        for (int d0 = 0; d0 < 8; ++d0) {
            bf16x8 v0 = *(const bf16x8*)&VFt[(size_t)(((d0 * 2 + 0) * 64 + lane) * 8)];
            acc[d0] = __builtin_amdgcn_mfma_f32_16x16x32_bf16(pa0, v0, acc[d0], 0, 0, 0);
            bf16x8 v1 = *(const bf16x8*)&VFt[(size_t)(((d0 * 2 + 1) * 64 + lane) * 8)];
            acc[d0] = __builtin_amdgcn_mfma_f32_16x16x32_bf16(pa1, v1, acc[d0], 0, 0, 0);
        }
    }

    // ---- epilogue: D-frag row=4hi+r, col=d0*16+m ----
    float* Ob = O + (size_t)bh * n * D;
    if (multi) {
        #pragma unroll
        for (int d0 = 0; d0 < 8; ++d0)
            #pragma unroll
            for (int r = 0; r < 4; ++r)
                unsafeAtomicAdd(&Ob[(size_t)(qrow0 + 4 * hi + r) * D + d0 * 16 + m],
                                acc[d0][r]);
    } else {
        #pragma unroll
        for (int d0 = 0; d0 < 8; ++d0)
            #pragma unroll
            for (int r = 0; r < 4; ++r)
                Ob[(size_t)(qrow0 + 4 * hi + r) * D + d0 * 16 + m] = acc[d0][r];
    }
}

extern "C" void kernel_launch(void* const* d_in, const int* in_sizes, int n_in,
                              void* d_out, int out_size, void* d_ws, size_t ws_size,
                              hipStream_t stream) {
    const float* q = (const float*)d_in[0];
    const float* k = (const float*)d_in[1];
    const float* v = (const float*)d_in[2];
    float* out = (float*)d_out;
    int total = in_sizes[0];          // b*h*n*d = 16*n*128
    int n = total / (16 * 128);
    int nqt = n / BQ;

    uint16_t* KF = (uint16_t*)d_ws;                       // 16*n*128 bf16
    uint16_t* VF = KF + (size_t)16 * n * D;               // 16*n*128 bf16

    hipMemsetAsync(d_out, 0, (size_t)out_size * sizeof(float), stream);
    la_prep<<<dim3(n / BK, 16), 256, 0, stream>>>(k, v, KF, VF, n);

    int gx = 0;
    for (int t = 0; t < nqt; ++t) gx += t / NCH + 1;      // chunks per q-tile
    la_main<<<dim3(gx, 16), 256, 0, stream>>>(q, KF, VF, out, n, nqt);
}